// Round 8
// baseline (261.281 us; speedup 1.0000x reference)
//
#include <hip/hip_runtime.h>
#include <math.h>

// Problem constants (fixed by the reference problem instance).
#define SDIM 64               // spike waveform length S
#define KCL  32               // num_clusters K
#define NPART (KCL*SDIM*2 + KCL)  // 4128 partials: sum[K*S] ++ sq[K*S] ++ cnt[K]
#define FACTOR_D 3.0          // second_match_factor
#define MAXDIST_TH 1280.0     // MAX_DIST * S = 20 * 64
#define MATCHED2_F 2.0f       // SPIKE_MATCHED_2

#define SB 1024               // stats grid (4 blocks/CU, thread-limited)
#define ST 512                // stats threads = 8 waves
#define BATCH 128             // rows staged per batch (32 KB LDS)

// ---------------------------------------------------------------------------
// P1: owner-computes segment sums, zero atomics. (UNCHANGED from R7 for
// attribution — R8 rewrites only the assign path.)
// ---------------------------------------------------------------------------
__global__ __launch_bounds__(ST) void stats_kernel(
    const float* __restrict__ spikes, const int* __restrict__ sortidx,
    float* __restrict__ pws, int n)
{
  __shared__ float rows[BATCH * SDIM];   // 32 KB, linear [row][col]
  const int lane  = threadIdx.x & 63;
  const int w     = threadIdx.x >> 6;    // wave 0..7
  const int cbase = w * 4;               // first owned cluster

  float s0=0,s1=0,s2=0,s3=0;             // per-lane column sums, 4 clusters
  float q0=0,q1=0,q2=0,q3=0;             // column sums of squares
  float cn0=0,cn1=0,cn2=0,cn3=0;         // row counts (wave-uniform)

  const long long nbatch = ((long long)n + BATCH - 1) / BATCH;
  const size_t gmax = (size_t)n * SDIM * sizeof(float) - 16;

  float4 v0, v1, v2, v3;                 // staged-batch registers
  int ida, idb;                          // cluster ids rows 0..63 / 64..127

#define LOADBATCH(B)                                                         \
  {                                                                          \
    const long long bsafe = ((B) < nbatch) ? (B) : 0;                        \
    size_t g0 = (size_t)bsafe * BATCH * SDIM * sizeof(float) +               \
                (size_t)threadIdx.x * 16;                                    \
    size_t g1 = g0 + 8192, g2 = g0 + 16384, g3 = g0 + 24576;                 \
    if (g0 > gmax) g0 = gmax;                                                \
    if (g1 > gmax) g1 = gmax;                                                \
    if (g2 > gmax) g2 = gmax;                                                \
    if (g3 > gmax) g3 = gmax;                                                \
    v0 = *reinterpret_cast<const float4*>((const char*)spikes + g0);         \
    v1 = *reinterpret_cast<const float4*>((const char*)spikes + g1);         \
    v2 = *reinterpret_cast<const float4*>((const char*)spikes + g2);         \
    v3 = *reinterpret_cast<const float4*>((const char*)spikes + g3);         \
    const long long ra = bsafe * BATCH + lane, rb = ra + 64;                 \
    ida = ((B) < nbatch && ra < n) ? sortidx[ra] : -1;                       \
    idb = ((B) < nbatch && rb < n) ? sortidx[rb] : -1;                       \
  }

#define POPLOOP(m0,m1,m2,m3,BASE)                                            \
  while (m0 | m1 | m2 | m3) {                                                \
    const bool e0 = m0 != 0, e1 = m1 != 0, e2 = m2 != 0, e3 = m3 != 0;       \
    const int b0 = e0 ? __ffsll(m0) - 1 : 0;                                 \
    const int b1 = e1 ? __ffsll(m1) - 1 : 0;                                 \
    const int b2 = e2 ? __ffsll(m2) - 1 : 0;                                 \
    const int b3 = e3 ? __ffsll(m3) - 1 : 0;                                 \
    m0 &= m0 - 1; m1 &= m1 - 1; m2 &= m2 - 1; m3 &= m3 - 1;                  \
    const float x0 = rows[((BASE) + b0) * SDIM + lane];                      \
    const float x1 = rows[((BASE) + b1) * SDIM + lane];                      \
    const float x2 = rows[((BASE) + b2) * SDIM + lane];                      \
    const float x3 = rows[((BASE) + b3) * SDIM + lane];                      \
    const float y0 = e0 ? x0 : 0.0f, y1 = e1 ? x1 : 0.0f;                    \
    const float y2 = e2 ? x2 : 0.0f, y3 = e3 ? x3 : 0.0f;                    \
    s0 += y0; q0 = fmaf(y0, x0, q0); cn0 += e0 ? 1.0f : 0.0f;                \
    s1 += y1; q1 = fmaf(y1, x1, q1); cn1 += e1 ? 1.0f : 0.0f;                \
    s2 += y2; q2 = fmaf(y2, x2, q2); cn2 += e2 ? 1.0f : 0.0f;                \
    s3 += y3; q3 = fmaf(y3, x3, q3); cn3 += e3 ? 1.0f : 0.0f;                \
  }

  long long bi = blockIdx.x;
  LOADBATCH(bi);                         // prologue

  for (; bi < nbatch; bi += gridDim.x) {
    __syncthreads();                     // (1) prev batch fully consumed
    {
      char* lb = (char*)rows + (size_t)threadIdx.x * 16;
      *reinterpret_cast<float4*>(lb)         = v0;
      *reinterpret_cast<float4*>(lb + 8192)  = v1;
      *reinterpret_cast<float4*>(lb + 16384) = v2;
      *reinterpret_cast<float4*>(lb + 24576) = v3;
    }
    const int cA = ida, cB = idb;        // save ids before regs are reused
    __syncthreads();                     // (2) batch staged

    LOADBATCH(bi + gridDim.x);           // next loads in flight across poploop

    unsigned long long mA0 = __ballot(cA == cbase + 0);
    unsigned long long mA1 = __ballot(cA == cbase + 1);
    unsigned long long mA2 = __ballot(cA == cbase + 2);
    unsigned long long mA3 = __ballot(cA == cbase + 3);
    unsigned long long mB0 = __ballot(cB == cbase + 0);
    unsigned long long mB1 = __ballot(cB == cbase + 1);
    unsigned long long mB2 = __ballot(cB == cbase + 2);
    unsigned long long mB3 = __ballot(cB == cbase + 3);
    if (w == 0) { mA0 = 0; mB0 = 0; }    // cluster 0: stats unused

    POPLOOP(mA0, mA1, mA2, mA3, 0)
    POPLOOP(mB0, mB1, mB2, mB3, 64)
  }
#undef LOADBATCH
#undef POPLOOP

  float* pb = pws + (size_t)blockIdx.x * NPART;
  pb[(cbase + 0) * SDIM + lane] = s0;
  pb[(cbase + 1) * SDIM + lane] = s1;
  pb[(cbase + 2) * SDIM + lane] = s2;
  pb[(cbase + 3) * SDIM + lane] = s3;
  pb[KCL * SDIM + (cbase + 0) * SDIM + lane] = q0;
  pb[KCL * SDIM + (cbase + 1) * SDIM + lane] = q1;
  pb[KCL * SDIM + (cbase + 2) * SDIM + lane] = q2;
  pb[KCL * SDIM + (cbase + 3) * SDIM + lane] = q3;
  if (lane == 0) {
    pb[2 * KCL * SDIM + cbase + 0] = cn0;
    pb[2 * KCL * SDIM + cbase + 1] = cn1;
    pb[2 * KCL * SDIM + cbase + 2] = cn2;
    pb[2 * KCL * SDIM + cbase + 3] = cn3;
  }
}

// ---------------------------------------------------------------------------
// P2: deterministic tree reduce of f32 block partials -> f64 gstats[4128].
// Also zeroes the assign-queue counter (runs before scanq on the stream).
// ---------------------------------------------------------------------------
__global__ __launch_bounds__(1024) void reduce_kernel(
    const float* __restrict__ pws, double* __restrict__ gstats,
    int* __restrict__ qcount, int nb)
{
  if (blockIdx.x == 0 && threadIdx.x == 0) *qcount = 0;
  __shared__ double s_acc[16][64];
  const int lane = threadIdx.x & 63;
  const int w    = threadIdx.x >> 6;
  const int u    = blockIdx.x * 64 + lane;
  double acc = 0.0;
  if (u < NPART)
    for (int b = w; b < nb; b += 16)
      acc += (double)pws[(size_t)b * NPART + u];
  s_acc[w][lane] = acc;
  __syncthreads();
  if (w == 0 && u < NPART) {
    double t = 0.0;
#pragma unroll
    for (int j = 0; j < 16; ++j) t += s_acc[j][lane];
    gstats[u] = t;
  }
}

// ---------------------------------------------------------------------------
// P3: finalize means (f32, c-major [c][s] for distq), t2, thr = 3*std, valid
// ---------------------------------------------------------------------------
__global__ __launch_bounds__(256) void finalize_kernel(
    const double* __restrict__ gstats, float* __restrict__ means_cs,
    double* __restrict__ t2, double* __restrict__ thr, int* __restrict__ validk)
{
  __shared__ double s_var[KCL], s_t2[KCL];
  if (threadIdx.x < KCL) { s_var[threadIdx.x] = 0.0; s_t2[threadIdx.x] = 0.0; }
  __syncthreads();
  const double* gsum = gstats;
  const double* gsq  = gstats + KCL * SDIM;
  const double* gcnt = gstats + 2 * KCL * SDIM;
  for (int i = threadIdx.x; i < KCL * SDIM; i += blockDim.x) {
    const int c = i / SDIM;
    const double cnt  = gcnt[c];
    const double safe = fmax(cnt, 1.0);
    const double m    = gsum[i] / safe;
    const double var  = gsq[i] / safe - m * m;
    means_cs[i] = (float)m;              // [c][s] c-major
    unsafeAtomicAdd(&s_var[c], var);
    unsafeAtomicAdd(&s_t2[c], m * m);
  }
  __syncthreads();
  if (threadIdx.x < KCL) {
    const int c = threadIdx.x;
    thr[c]    = FACTOR_D * sqrt(fmax(s_var[c], 0.0));
    t2[c]     = s_t2[c];
    validk[c] = (c != 0 && gcnt[c] > 0.0) ? 1 : 0;
  }
}

// ---------------------------------------------------------------------------
// P4a: streaming scan. Matched rows: pass-through stores. Unmatched rows:
// enqueue row id (wave-aggregated device atomicAdd; queue order is
// nondeterministic but per-row processing in P4b is order-independent).
// ---------------------------------------------------------------------------
__global__ __launch_bounds__(256) void scanq_kernel(
    const int* __restrict__ sortidx, const int* __restrict__ matchidx,
    const float* __restrict__ distance, float* __restrict__ out,
    int* __restrict__ queue, int* __restrict__ qcount, int n)
{
  const int stride = gridDim.x * blockDim.x;
  for (int i = blockIdx.x * blockDim.x + threadIdx.x; i < n; i += stride) {
    const int cv = sortidx[i];
    if (cv != 0) {
      out[i]          = (float)cv;
      out[n + i]      = (float)matchidx[i];
      out[2LL*n + i]  = distance[i];
    } else {
      const int pos = atomicAdd(qcount, 1);
      queue[pos] = i;
    }
  }
}

// ---------------------------------------------------------------------------
// P4b: compacted distance/argmin. One wave per 64 queued rows; LANE = ROW.
// Row held in 16 float4 regs; 32 dots as sequential f32 fmaf (same per-(row,c)
// order as the previous passing kernel); means broadcast from LDS ([c][s],
// wave-uniform ds_read_b128); per-lane scalar argmin, ascending c with strict
// '<' = first-index tie-break; f64 combine/sqrt/threshold as before.
// ---------------------------------------------------------------------------
__global__ __launch_bounds__(256) void distq_kernel(
    const float* __restrict__ spikes, const float* __restrict__ means_cs,
    const double* __restrict__ t2g, const double* __restrict__ thrg,
    const int* __restrict__ validk, const int* __restrict__ queue,
    const int* __restrict__ qcount, float* __restrict__ out, int n)
{
  __shared__ float  s_m[KCL][SDIM];
  __shared__ double s_t2[KCL], s_thr[KCL];
  __shared__ int    s_valid[KCL];
  for (int i = threadIdx.x; i < KCL * SDIM; i += blockDim.x)
    (&s_m[0][0])[i] = means_cs[i];
  if (threadIdx.x < KCL) {
    s_t2[threadIdx.x]    = t2g[threadIdx.x];
    s_thr[threadIdx.x]   = thrg[threadIdx.x];
    s_valid[threadIdx.x] = validk[threadIdx.x];
  }
  __syncthreads();

  const int lane = threadIdx.x & 63;
  const int wv   = threadIdx.x >> 6;
  const int qn   = *qcount;
  const int gw0  = blockIdx.x * (blockDim.x >> 6) + wv;
  const int nw   = gridDim.x * (blockDim.x >> 6);

  for (long long base = (long long)gw0 * 64; base < qn;
       base += (long long)nw * 64) {
    const long long qi = base + lane;
    const bool on = qi < qn;
    const int r = on ? queue[qi] : 0;

    float4 xv[16];
    const float4* rp = reinterpret_cast<const float4*>(
        spikes + (size_t)r * SDIM);
#pragma unroll
    for (int s4 = 0; s4 < 16; ++s4) xv[s4] = rp[s4];

    float x2 = 0.0f;
#pragma unroll
    for (int s4 = 0; s4 < 16; ++s4) {
      x2 = fmaf(xv[s4].x, xv[s4].x, x2);
      x2 = fmaf(xv[s4].y, xv[s4].y, x2);
      x2 = fmaf(xv[s4].z, xv[s4].z, x2);
      x2 = fmaf(xv[s4].w, xv[s4].w, x2);
    }

    double best = (double)INFINITY;
    int bidx = 0;
    for (int c = 0; c < KCL; ++c) {
      float dot = 0.0f;
#pragma unroll
      for (int s4 = 0; s4 < 16; ++s4) {
        const float4 m = *reinterpret_cast<const float4*>(&s_m[c][s4 * 4]);
        dot = fmaf(xv[s4].x, m.x, dot);
        dot = fmaf(xv[s4].y, m.y, dot);
        dot = fmaf(xv[s4].z, m.z, dot);
        dot = fmaf(xv[s4].w, m.w, dot);
      }
      if (s_valid[c]) {
        const double d2 = (double)x2 - 2.0 * (double)dot + s_t2[c];
        double dist = sqrt(fmax(d2, 1e-12));
        if (dist <= s_thr[c] && dist < best) { best = dist; bidx = c; }
      }
    }

    if (on) {
      const int mz = (best >= MAXDIST_TH) ? 0 : bidx;
      out[r]          = (float)mz;
      out[n + r]      = MATCHED2_F;
      out[2LL*n + r]  = (float)best;
    }
  }
}

// ---------------------------------------------------------------------------
extern "C" void kernel_launch(void* const* d_in, const int* in_sizes, int n_in,
                              void* d_out, int out_size, void* d_ws, size_t ws_size,
                              hipStream_t stream) {
  const float* spikes   = (const float*)d_in[0];
  const int*   sortidx  = (const int*)d_in[1];
  const int*   matchidx = (const int*)d_in[2];
  const float* distance = (const float*)d_in[3];
  const int n = in_sizes[1];
  if (n <= 0) return;
  float* out = (float*)d_out;

  // ws: pws f32[SB*NPART] | gstats f64[NPART] | means_cs f32[2048]
  //     | t2 f64[32] | thr f64[32] | validk i32[32] | qcount i32 | queue i32[n]
  float*  pws      = (float*)d_ws;
  double* gstats   = (double*)((char*)d_ws +
                               (((size_t)SB * NPART * sizeof(float) + 15) & ~15ull));
  float*  means_cs = (float*)(gstats + NPART);
  double* t2       = (double*)(((size_t)(means_cs + KCL * SDIM) + 7) & ~7ull);
  double* thr      = t2 + KCL;
  int*    validk   = (int*)(thr + KCL);
  int*    qcount   = validk + KCL;
  int*    queue    = qcount + 1;

  stats_kernel<<<SB, ST, 0, stream>>>(spikes, sortidx, pws, n);
  reduce_kernel<<<(NPART + 63) / 64, 1024, 0, stream>>>(pws, gstats, qcount, SB);
  finalize_kernel<<<1, 256, 0, stream>>>(gstats, means_cs, t2, thr, validk);
  scanq_kernel<<<2048, 256, 0, stream>>>(sortidx, matchidx, distance, out,
                                         queue, qcount, n);
  distq_kernel<<<2048, 256, 0, stream>>>(spikes, means_cs, t2, thr, validk,
                                         queue, qcount, out, n);
}

// Round 9
// 109.875 us; speedup vs baseline: 2.3780x; 2.3780x over previous
//
#include <hip/hip_runtime.h>
#include <math.h>

// Problem constants (fixed by the reference problem instance).
#define SDIM 64               // spike waveform length S
#define KCL  32               // num_clusters K
#define NPART (KCL*SDIM*2 + KCL)  // 4128 partials: sum[K*S] ++ sq[K*S] ++ cnt[K]
#define FACTOR_D 3.0          // second_match_factor
#define MAXDIST_TH 1280.0     // MAX_DIST * S = 20 * 64
#define MATCHED2_F 2.0f       // SPIKE_MATCHED_2

#define SB 1024               // stats grid (4 blocks/CU, thread-limited)
#define ST 512                // stats threads = 8 waves
#define BATCH 128             // rows staged per batch (32 KB LDS)

#define ACHUNK 512            // rows per assign block (LDS id-buffer bound)

// ---------------------------------------------------------------------------
// P1: owner-computes segment sums, zero atomics. (UNCHANGED from R7/R8 for
// attribution — R9 replaces only the assign path.)
// ---------------------------------------------------------------------------
__global__ __launch_bounds__(ST) void stats_kernel(
    const float* __restrict__ spikes, const int* __restrict__ sortidx,
    float* __restrict__ pws, int n)
{
  __shared__ float rows[BATCH * SDIM];   // 32 KB, linear [row][col]
  const int lane  = threadIdx.x & 63;
  const int w     = threadIdx.x >> 6;    // wave 0..7
  const int cbase = w * 4;               // first owned cluster

  float s0=0,s1=0,s2=0,s3=0;             // per-lane column sums, 4 clusters
  float q0=0,q1=0,q2=0,q3=0;             // column sums of squares
  float cn0=0,cn1=0,cn2=0,cn3=0;         // row counts (wave-uniform)

  const long long nbatch = ((long long)n + BATCH - 1) / BATCH;
  const size_t gmax = (size_t)n * SDIM * sizeof(float) - 16;

  float4 v0, v1, v2, v3;                 // staged-batch registers
  int ida, idb;                          // cluster ids rows 0..63 / 64..127

#define LOADBATCH(B)                                                         \
  {                                                                          \
    const long long bsafe = ((B) < nbatch) ? (B) : 0;                        \
    size_t g0 = (size_t)bsafe * BATCH * SDIM * sizeof(float) +               \
                (size_t)threadIdx.x * 16;                                    \
    size_t g1 = g0 + 8192, g2 = g0 + 16384, g3 = g0 + 24576;                 \
    if (g0 > gmax) g0 = gmax;                                                \
    if (g1 > gmax) g1 = gmax;                                                \
    if (g2 > gmax) g2 = gmax;                                                \
    if (g3 > gmax) g3 = gmax;                                                \
    v0 = *reinterpret_cast<const float4*>((const char*)spikes + g0);         \
    v1 = *reinterpret_cast<const float4*>((const char*)spikes + g1);         \
    v2 = *reinterpret_cast<const float4*>((const char*)spikes + g2);         \
    v3 = *reinterpret_cast<const float4*>((const char*)spikes + g3);         \
    const long long ra = bsafe * BATCH + lane, rb = ra + 64;                 \
    ida = ((B) < nbatch && ra < n) ? sortidx[ra] : -1;                       \
    idb = ((B) < nbatch && rb < n) ? sortidx[rb] : -1;                       \
  }

#define POPLOOP(m0,m1,m2,m3,BASE)                                            \
  while (m0 | m1 | m2 | m3) {                                                \
    const bool e0 = m0 != 0, e1 = m1 != 0, e2 = m2 != 0, e3 = m3 != 0;       \
    const int b0 = e0 ? __ffsll(m0) - 1 : 0;                                 \
    const int b1 = e1 ? __ffsll(m1) - 1 : 0;                                 \
    const int b2 = e2 ? __ffsll(m2) - 1 : 0;                                 \
    const int b3 = e3 ? __ffsll(m3) - 1 : 0;                                 \
    m0 &= m0 - 1; m1 &= m1 - 1; m2 &= m2 - 1; m3 &= m3 - 1;                  \
    const float x0 = rows[((BASE) + b0) * SDIM + lane];                      \
    const float x1 = rows[((BASE) + b1) * SDIM + lane];                      \
    const float x2 = rows[((BASE) + b2) * SDIM + lane];                      \
    const float x3 = rows[((BASE) + b3) * SDIM + lane];                      \
    const float y0 = e0 ? x0 : 0.0f, y1 = e1 ? x1 : 0.0f;                    \
    const float y2 = e2 ? x2 : 0.0f, y3 = e3 ? x3 : 0.0f;                    \
    s0 += y0; q0 = fmaf(y0, x0, q0); cn0 += e0 ? 1.0f : 0.0f;                \
    s1 += y1; q1 = fmaf(y1, x1, q1); cn1 += e1 ? 1.0f : 0.0f;                \
    s2 += y2; q2 = fmaf(y2, x2, q2); cn2 += e2 ? 1.0f : 0.0f;                \
    s3 += y3; q3 = fmaf(y3, x3, q3); cn3 += e3 ? 1.0f : 0.0f;                \
  }

  long long bi = blockIdx.x;
  LOADBATCH(bi);                         // prologue

  for (; bi < nbatch; bi += gridDim.x) {
    __syncthreads();                     // (1) prev batch fully consumed
    {
      char* lb = (char*)rows + (size_t)threadIdx.x * 16;
      *reinterpret_cast<float4*>(lb)         = v0;
      *reinterpret_cast<float4*>(lb + 8192)  = v1;
      *reinterpret_cast<float4*>(lb + 16384) = v2;
      *reinterpret_cast<float4*>(lb + 24576) = v3;
    }
    const int cA = ida, cB = idb;        // save ids before regs are reused
    __syncthreads();                     // (2) batch staged

    LOADBATCH(bi + gridDim.x);           // next loads in flight across poploop

    unsigned long long mA0 = __ballot(cA == cbase + 0);
    unsigned long long mA1 = __ballot(cA == cbase + 1);
    unsigned long long mA2 = __ballot(cA == cbase + 2);
    unsigned long long mA3 = __ballot(cA == cbase + 3);
    unsigned long long mB0 = __ballot(cB == cbase + 0);
    unsigned long long mB1 = __ballot(cB == cbase + 1);
    unsigned long long mB2 = __ballot(cB == cbase + 2);
    unsigned long long mB3 = __ballot(cB == cbase + 3);
    if (w == 0) { mA0 = 0; mB0 = 0; }    // cluster 0: stats unused

    POPLOOP(mA0, mA1, mA2, mA3, 0)
    POPLOOP(mB0, mB1, mB2, mB3, 64)
  }
#undef LOADBATCH
#undef POPLOOP

  float* pb = pws + (size_t)blockIdx.x * NPART;
  pb[(cbase + 0) * SDIM + lane] = s0;
  pb[(cbase + 1) * SDIM + lane] = s1;
  pb[(cbase + 2) * SDIM + lane] = s2;
  pb[(cbase + 3) * SDIM + lane] = s3;
  pb[KCL * SDIM + (cbase + 0) * SDIM + lane] = q0;
  pb[KCL * SDIM + (cbase + 1) * SDIM + lane] = q1;
  pb[KCL * SDIM + (cbase + 2) * SDIM + lane] = q2;
  pb[KCL * SDIM + (cbase + 3) * SDIM + lane] = q3;
  if (lane == 0) {
    pb[2 * KCL * SDIM + cbase + 0] = cn0;
    pb[2 * KCL * SDIM + cbase + 1] = cn1;
    pb[2 * KCL * SDIM + cbase + 2] = cn2;
    pb[2 * KCL * SDIM + cbase + 3] = cn3;
  }
}

// ---------------------------------------------------------------------------
// P2: deterministic tree reduce of f32 block partials -> f64 gstats[4128].
// ---------------------------------------------------------------------------
__global__ __launch_bounds__(1024) void reduce_kernel(
    const float* __restrict__ pws, double* __restrict__ gstats, int nb)
{
  __shared__ double s_acc[16][64];
  const int lane = threadIdx.x & 63;
  const int w    = threadIdx.x >> 6;
  const int u    = blockIdx.x * 64 + lane;
  double acc = 0.0;
  if (u < NPART)
    for (int b = w; b < nb; b += 16)
      acc += (double)pws[(size_t)b * NPART + u];
  s_acc[w][lane] = acc;
  __syncthreads();
  if (w == 0 && u < NPART) {
    double t = 0.0;
#pragma unroll
    for (int j = 0; j < 16; ++j) t += s_acc[j][lane];
    gstats[u] = t;
  }
}

// ---------------------------------------------------------------------------
// P3: finalize means (f32, c-major [c][s]), t2, thr = 3*std, valid (f64)
// ---------------------------------------------------------------------------
__global__ __launch_bounds__(256) void finalize_kernel(
    const double* __restrict__ gstats, float* __restrict__ means_cs,
    double* __restrict__ t2, double* __restrict__ thr, int* __restrict__ validk)
{
  __shared__ double s_var[KCL], s_t2[KCL];
  if (threadIdx.x < KCL) { s_var[threadIdx.x] = 0.0; s_t2[threadIdx.x] = 0.0; }
  __syncthreads();
  const double* gsum = gstats;
  const double* gsq  = gstats + KCL * SDIM;
  const double* gcnt = gstats + 2 * KCL * SDIM;
  for (int i = threadIdx.x; i < KCL * SDIM; i += blockDim.x) {
    const int c = i / SDIM;
    const double cnt  = gcnt[c];
    const double safe = fmax(cnt, 1.0);
    const double m    = gsum[i] / safe;
    const double var  = gsq[i] / safe - m * m;
    means_cs[i] = (float)m;              // [c][s] c-major
    unsafeAtomicAdd(&s_var[c], var);
    unsafeAtomicAdd(&s_t2[c], m * m);
  }
  __syncthreads();
  if (threadIdx.x < KCL) {
    const int c = threadIdx.x;
    thr[c]    = FACTOR_D * sqrt(fmax(s_var[c], 0.0));
    t2[c]     = s_t2[c];
    validk[c] = (c != 0 && gcnt[c] > 0.0) ? 1 : 0;
  }
}

// ---------------------------------------------------------------------------
// P4: merged scan + distance. Each block owns a contiguous ACHUNK-row range:
// pass-through stores for matched rows; unmatched row ids collected into an
// LDS queue (LDS atomic, ~16/block — trivial); then thread-per-row distance/
// argmin against LDS-resident means. NO global atomics anywhere.
// Per-row arithmetic is bit-identical to R8's distq (passing, absmax .03):
// sequential f32 x2 and dot, f64 combine/sqrt, '<=thr' mask, strict '<'
// ascending-c argmin (first-index tie-break), MAX_DIST override.
// LDS-queue ordering is nondeterministic but per-row results are pure ->
// output deterministic.
// ---------------------------------------------------------------------------
__global__ __launch_bounds__(256) void assign2_kernel(
    const float* __restrict__ spikes, const int* __restrict__ sortidx,
    const int* __restrict__ matchidx, const float* __restrict__ distance,
    const float* __restrict__ means_cs, const double* __restrict__ t2g,
    const double* __restrict__ thrg, const int* __restrict__ validk,
    float* __restrict__ out, int n)
{
  __shared__ float  s_m[KCL][SDIM];      // 8 KB, [c][s]
  __shared__ double s_t2[KCL], s_thr[KCL];
  __shared__ int    s_valid[KCL];
  __shared__ int    ids[ACHUNK];
  __shared__ int    scnt;

  for (int i = threadIdx.x; i < KCL * SDIM; i += blockDim.x)
    (&s_m[0][0])[i] = means_cs[i];
  if (threadIdx.x < KCL) {
    s_t2[threadIdx.x]    = t2g[threadIdx.x];
    s_thr[threadIdx.x]   = thrg[threadIdx.x];
    s_valid[threadIdx.x] = validk[threadIdx.x];
  }
  if (threadIdx.x == 0) scnt = 0;
  __syncthreads();

  const long long start = (long long)blockIdx.x * ACHUNK;
  long long end = start + ACHUNK; if (end > n) end = n;

  // scan phase: pass-through + LDS enqueue
  for (long long i = start + threadIdx.x; i < end; i += blockDim.x) {
    const int cv = sortidx[i];
    if (cv != 0) {
      out[i]           = (float)cv;
      out[n + i]       = (float)matchidx[i];
      out[2LL * n + i] = distance[i];
    } else {
      const int p = atomicAdd(&scnt, 1);   // LDS atomic, rare
      ids[p] = (int)i;
    }
  }
  __syncthreads();
  const int cnt = scnt;

  // dist phase: thread-per-row
  for (int base = 0; base < cnt; base += blockDim.x) {
    const int j = base + threadIdx.x;
    if (j >= cnt) break;
    const int r = ids[j];

    float4 xv[16];
    const float4* rp = reinterpret_cast<const float4*>(
        spikes + (size_t)r * SDIM);
#pragma unroll
    for (int s4 = 0; s4 < 16; ++s4) xv[s4] = rp[s4];

    float x2 = 0.0f;
#pragma unroll
    for (int s4 = 0; s4 < 16; ++s4) {
      x2 = fmaf(xv[s4].x, xv[s4].x, x2);
      x2 = fmaf(xv[s4].y, xv[s4].y, x2);
      x2 = fmaf(xv[s4].z, xv[s4].z, x2);
      x2 = fmaf(xv[s4].w, xv[s4].w, x2);
    }

    double best = (double)INFINITY;
    int bidx = 0;
    for (int c = 0; c < KCL; ++c) {
      float dot = 0.0f;
#pragma unroll
      for (int s4 = 0; s4 < 16; ++s4) {
        const float4 m = *reinterpret_cast<const float4*>(&s_m[c][s4 * 4]);
        dot = fmaf(xv[s4].x, m.x, dot);
        dot = fmaf(xv[s4].y, m.y, dot);
        dot = fmaf(xv[s4].z, m.z, dot);
        dot = fmaf(xv[s4].w, m.w, dot);
      }
      if (s_valid[c]) {
        const double d2 = (double)x2 - 2.0 * (double)dot + s_t2[c];
        double dist = sqrt(fmax(d2, 1e-12));
        if (dist <= s_thr[c] && dist < best) { best = dist; bidx = c; }
      }
    }

    const int mz = (best >= MAXDIST_TH) ? 0 : bidx;
    out[r]           = (float)mz;
    out[n + r]       = MATCHED2_F;
    out[2LL * n + r] = (float)best;
  }
}

// ---------------------------------------------------------------------------
extern "C" void kernel_launch(void* const* d_in, const int* in_sizes, int n_in,
                              void* d_out, int out_size, void* d_ws, size_t ws_size,
                              hipStream_t stream) {
  const float* spikes   = (const float*)d_in[0];
  const int*   sortidx  = (const int*)d_in[1];
  const int*   matchidx = (const int*)d_in[2];
  const float* distance = (const float*)d_in[3];
  const int n = in_sizes[1];
  if (n <= 0) return;
  float* out = (float*)d_out;

  // ws: pws f32[SB*NPART] | gstats f64[NPART] | means_cs f32[2048]
  //     | t2 f64[32] | thr f64[32] | validk i32[32]
  float*  pws      = (float*)d_ws;
  double* gstats   = (double*)((char*)d_ws +
                               (((size_t)SB * NPART * sizeof(float) + 15) & ~15ull));
  float*  means_cs = (float*)(gstats + NPART);
  double* t2       = (double*)(((size_t)(means_cs + KCL * SDIM) + 7) & ~7ull);
  double* thr      = t2 + KCL;
  int*    validk   = (int*)(thr + KCL);

  const int ablocks = (n + ACHUNK - 1) / ACHUNK;

  stats_kernel<<<SB, ST, 0, stream>>>(spikes, sortidx, pws, n);
  reduce_kernel<<<(NPART + 63) / 64, 1024, 0, stream>>>(pws, gstats, SB);
  finalize_kernel<<<1, 256, 0, stream>>>(gstats, means_cs, t2, thr, validk);
  assign2_kernel<<<ablocks, 256, 0, stream>>>(spikes, sortidx, matchidx,
                                              distance, means_cs, t2, thr,
                                              validk, out, n);
}